// Round 1
// baseline (16243.440 us; speedup 1.0000x reference)
//
#include <hip/hip_runtime.h>
#include <cstdint>
#include <cstddef>

// ---------------------------------------------------------------------------
// EnDeModel: GRU encoder (365 steps) -> GRU decoder (90 steps) -> SIRD rollout
// Persistent-grid design: 256 WGs (one per CU) x 512 threads.
//  - Encoder Whh slice (24 rows) lives in fp32 registers (3 rows/wave).
//  - Decoder Wih+Whh slice (48 rows) lives in packed-bf16 registers (6 rows/wave).
//  - gi for the encoder collapses to u_t * p + q  (p = Wih@Wb, q = Wih@bb + bih).
//  - Per-step device-wide barrier: per-WG flag store + all-WG flag poll
//    (no RMW hotspot), agent-scope atomics for cross-XCD coherence.
// ---------------------------------------------------------------------------

#define HID   2048
#define T_ENC 365
#define F_DEC 90
#define NWG   256
#define NTH   512

// ws layout (4-byte units)
#define WS_P     0                 // p[6144]
#define WS_Q     6144              // q[6144]
#define WS_HBUF  12288             // h_buf[2][2048]
#define WS_DX    16384             // dx[2][2048]
#define WS_DH    20480             // dh[2][2048]
#define WS_BETA  24576             // beta_acc[90] (pad to 128)
#define WS_FLAGS 24704             // flags[455][256] ints
#define N_FLAGS  (455 * 256)

__device__ __forceinline__ float sigm(float x) {
    return 1.0f / (1.0f + __expf(-x));
}
__device__ __forceinline__ float tanh_f(float x) {
    // stable: large |x| saturates correctly through inf
    return 1.0f - 2.0f / (1.0f + __expf(2.0f * x));
}
__device__ __forceinline__ unsigned bf16rne(float f) {
    unsigned x = __float_as_uint(f);
    return (x + 0x7fffu + ((x >> 16) & 1u)) >> 16;
}
__device__ __forceinline__ unsigned packbf(float lo, float hi) {
    return bf16rne(lo) | (bf16rne(hi) << 16);
}

__global__ void init_ws(int* z, int n) {
    for (int i = blockIdx.x * blockDim.x + threadIdx.x; i < n;
         i += gridDim.x * blockDim.x)
        z[i] = 0;
}

// p[r] = enc_Wih[r,:] @ Wb ; q[r] = enc_Wih[r,:] @ bb + enc_bih[r]
__global__ void prep_pq(const float* __restrict__ Wih, const float* __restrict__ Wb,
                        const float* __restrict__ bb, const float* __restrict__ bih,
                        float* __restrict__ p, float* __restrict__ q) {
    int wave = threadIdx.x >> 6, lane = threadIdx.x & 63;
    int row = blockIdx.x * 4 + wave;
    const float* wr = Wih + (size_t)row * HID;
    float ap = 0.f, aq = 0.f;
    for (int k = lane; k < HID; k += 64) {
        float w = wr[k];
        ap += w * Wb[k];
        aq += w * bb[k];
    }
#pragma unroll
    for (int m = 1; m < 64; m <<= 1) {
        ap += __shfl_xor(ap, m);
        aq += __shfl_xor(aq, m);
    }
    if (lane == 0) {
        p[row] = ap;
        q[row] = aq + bih[row];
    }
}

__device__ __forceinline__ void barrier_wait(const int* flags_t) {
    while (true) {
        int f = 1;
        if (threadIdx.x < NWG)
            f = __hip_atomic_load((int*)(flags_t + threadIdx.x),
                                  __ATOMIC_RELAXED, __HIP_MEMORY_SCOPE_AGENT);
        if (__syncthreads_count(f != 0) == NTH) break;
        __builtin_amdgcn_s_sleep(1);
    }
    __builtin_amdgcn_fence(__ATOMIC_ACQUIRE, "agent");
}

__device__ __forceinline__ void barrier_arrive(int* flags_t, int wg) {
    __builtin_amdgcn_fence(__ATOMIC_RELEASE, "agent");
    __syncthreads();
    if (threadIdx.x == 0)
        __hip_atomic_store(flags_t + wg, 1, __ATOMIC_RELAXED,
                           __HIP_MEMORY_SCOPE_AGENT);
}

__device__ __forceinline__ float agent_ld(const float* p_) {
    return __hip_atomic_load((float*)p_, __ATOMIC_RELAXED, __HIP_MEMORY_SCOPE_AGENT);
}
__device__ __forceinline__ void agent_st(float* p_, float v) {
    __hip_atomic_store(p_, v, __ATOMIC_RELAXED, __HIP_MEMORY_SCOPE_AGENT);
}

__global__ __launch_bounds__(NTH, 2) void persist(
    const float* __restrict__ hu, const float* __restrict__ encWhh,
    const float* __restrict__ encBhh, const float* __restrict__ decWih,
    const float* __restrict__ decWhh, const float* __restrict__ decBih,
    const float* __restrict__ decBhh, const float* __restrict__ Wa,
    const float* __restrict__ p, const float* __restrict__ q,
    float* h_buf, float* dx, float* dh, float* beta_acc, int* flags) {
    const int wg = blockIdx.x, tid = threadIdx.x;
    const int wave = tid >> 6, lane = tid & 63;
    const int j0 = wg * 8;

    __shared__ float h_lds[HID], x_lds[HID];
    __shared__ float g_l[48];
    __shared__ float p_l[24], q_l[24], ebhh[24], dbih[24], dbhh[24], wa_l[8];
    __shared__ float u_l[T_ENC];

    // --- LDS preloads (once) ---
    for (int idx = tid; idx < T_ENC; idx += NTH) u_l[idx] = hu[idx];
    if (tid < 24) {
        int g = tid >> 3, jj = tid & 7;
        int r = g * HID + j0 + jj;
        p_l[tid] = p[r];
        q_l[tid] = q[r];
        ebhh[tid] = encBhh[r];
        dbih[tid] = decBih[r];
        dbhh[tid] = decBhh[r];
    }
    if (tid < 8) wa_l[tid] = Wa[j0 + tid];

    // --- encoder Whh slice -> fp32 registers: 3 rows per wave ---
    // lane k-set: k in {4*lane + 256*i + e | i=0..7, e=0..3}
    float4 We[3][8];
#pragma unroll
    for (int rr = 0; rr < 3; rr++) {
        int l = wave * 3 + rr;
        int r = (l >> 3) * HID + j0 + (l & 7);
        const float* base = encWhh + (size_t)r * HID;
#pragma unroll
        for (int i = 0; i < 8; i++)
            We[rr][i] = *reinterpret_cast<const float4*>(base + 4 * lane + 256 * i);
    }
    __syncthreads();

    // =========================== encoder: 365 steps =========================
    for (int t = 0; t < T_ENC; t++) {
        if (t == 0) {
            for (int idx = tid; idx < HID; idx += NTH) h_lds[idx] = 0.f;
            __syncthreads();
        } else {
            barrier_wait(flags + (size_t)(t - 1) * NWG);
            const float* src = h_buf + (t & 1) * HID;
#pragma unroll
            for (int ii = 0; ii < 4; ii++) {
                int idx = ii * NTH + tid;
                h_lds[idx] = agent_ld(src + idx);
            }
            __syncthreads();
        }

        float4 hreg[8];
#pragma unroll
        for (int i = 0; i < 8; i++)
            hreg[i] = *reinterpret_cast<const float4*>(&h_lds[4 * lane + 256 * i]);

#pragma unroll
        for (int rr = 0; rr < 3; rr++) {
            float a0 = 0.f, a1 = 0.f, a2 = 0.f, a3 = 0.f;
#pragma unroll
            for (int i = 0; i < 8; i++) {
                float4 w = We[rr][i], h4 = hreg[i];
                a0 += w.x * h4.x;
                a1 += w.y * h4.y;
                a2 += w.z * h4.z;
                a3 += w.w * h4.w;
            }
            float v = (a0 + a1) + (a2 + a3);
#pragma unroll
            for (int m = 1; m < 64; m <<= 1) v += __shfl_xor(v, m);
            if (lane == 0) g_l[wave * 3 + rr] = v;
        }
        __syncthreads();

        if (tid < 8) {
            int jj = tid;
            float u = u_l[t];
            float gir = u * p_l[jj] + q_l[jj];
            float giz = u * p_l[8 + jj] + q_l[8 + jj];
            float gic = u * p_l[16 + jj] + q_l[16 + jj];
            float ghr = g_l[jj] + ebhh[jj];
            float ghz = g_l[8 + jj] + ebhh[8 + jj];
            float ghc = g_l[16 + jj] + ebhh[16 + jj];
            float r = sigm(gir + ghr);
            float z = sigm(giz + ghz);
            float c = tanh_f(gic + r * ghc);
            float hp = (1.f - z) * c + z * h_lds[j0 + jj];
            if (t < T_ENC - 1) {
                agent_st(h_buf + ((t + 1) & 1) * HID + j0 + jj, sigm(hp));
            } else {
                agent_st(dx + j0 + jj, hp);        // y  (raw hp)
                agent_st(dh + j0 + jj, sigm(hp));  // h_enc
            }
        }
        barrier_arrive(flags + (size_t)t * NWG, wg);
    }

    // --- decoder Wih+Whh slice -> packed bf16 registers: 6 rows per wave ---
    unsigned Wd[6][8][2];
#pragma unroll
    for (int rr = 0; rr < 6; rr++) {
        int l = wave * 6 + rr;
        const float* src;
        if (l < 24)
            src = decWih + (size_t)((l >> 3) * HID + j0 + (l & 7)) * HID;
        else {
            int l2 = l - 24;
            src = decWhh + (size_t)((l2 >> 3) * HID + j0 + (l2 & 7)) * HID;
        }
#pragma unroll
        for (int i = 0; i < 8; i++) {
            float4 w = *reinterpret_cast<const float4*>(src + 4 * lane + 256 * i);
            Wd[rr][i][0] = packbf(w.x, w.y);
            Wd[rr][i][1] = packbf(w.z, w.w);
        }
    }

    // =========================== decoder: 90 steps ==========================
    for (int s = 0; s < F_DEC; s++) {
        barrier_wait(flags + (size_t)(T_ENC - 1 + s) * NWG);
        {
            const float* sx = dx + (s & 1) * HID;
            const float* sh = dh + (s & 1) * HID;
#pragma unroll
            for (int ii = 0; ii < 8; ii++) {
                if (tid < 256) {
                    int idx = ii * 256 + tid;
                    x_lds[idx] = agent_ld(sx + idx);
                } else {
                    int idx = ii * 256 + (tid - 256);
                    h_lds[idx] = agent_ld(sh + idx);
                }
            }
            __syncthreads();
        }

        const float* vsrc = (wave < 4) ? x_lds : h_lds;
        float4 vreg[8];
#pragma unroll
        for (int i = 0; i < 8; i++)
            vreg[i] = *reinterpret_cast<const float4*>(&vsrc[4 * lane + 256 * i]);

#pragma unroll
        for (int rr = 0; rr < 6; rr++) {
            float a0 = 0.f, a1 = 0.f, a2 = 0.f, a3 = 0.f;
#pragma unroll
            for (int i = 0; i < 8; i++) {
                unsigned u0 = Wd[rr][i][0], u1 = Wd[rr][i][1];
                float4 v4 = vreg[i];
                a0 += __uint_as_float(u0 << 16) * v4.x;
                a1 += __uint_as_float(u0 & 0xffff0000u) * v4.y;
                a2 += __uint_as_float(u1 << 16) * v4.z;
                a3 += __uint_as_float(u1 & 0xffff0000u) * v4.w;
            }
            float v = (a0 + a1) + (a2 + a3);
#pragma unroll
            for (int m = 1; m < 64; m <<= 1) v += __shfl_xor(v, m);
            if (lane == 0) g_l[wave * 6 + rr] = v;
        }
        __syncthreads();

        if (tid < 8) {
            int jj = tid;
            float gir = g_l[jj] + dbih[jj];
            float giz = g_l[8 + jj] + dbih[8 + jj];
            float gic = g_l[16 + jj] + dbih[16 + jj];
            float ghr = g_l[24 + jj] + dbhh[jj];
            float ghz = g_l[32 + jj] + dbhh[8 + jj];
            float ghc = g_l[40 + jj] + dbhh[16 + jj];
            float r = sigm(gir + ghr);
            float z = sigm(giz + ghz);
            float c = tanh_f(gic + r * ghc);
            float hp = (1.f - z) * c + z * h_lds[j0 + jj];
            agent_st(dx + ((s + 1) & 1) * HID + j0 + jj, hp);
            agent_st(dh + ((s + 1) & 1) * HID + j0 + jj, hp);
            float bc = wa_l[jj] * hp;
            bc += __shfl_xor(bc, 1);
            bc += __shfl_xor(bc, 2);
            bc += __shfl_xor(bc, 4);
            if (jj == 0) atomicAdd(beta_acc + s, bc);
        }
        barrier_arrive(flags + (size_t)(T_ENC + s) * NWG, wg);
    }
}

__global__ void sird_k(const float* __restrict__ sird, const float* __restrict__ ba,
                       const int* __restrict__ ts_p,
                       const float* __restrict__ beta_acc, float* __restrict__ out) {
    if (blockIdx.x == 0 && threadIdx.x == 0) {
        float s = sird[0], i = sird[1], r = sird[2], d = sird[3], n = sird[4];
        float bl = 0.f;
        for (int t = 0; t < F_DEC; t++) {
            float b = 1.f / (1.f + expf(-(beta_acc[t] + ba[0])));
            bl = b;
            float si = s * i * b / n, ir = i * 0.05f, id = i * 0.01f;
            s -= si;
            i += si - ir - id;
            r += ir;
            d += id;
        }
        int ts = ts_p[0];
        float* foo = out + 5;
        for (int t = 0; t < ts - 1; t++) {
            float si = s * i * bl / n, ir = i * 0.05f, id = i * 0.01f;
            s -= si;
            i += si - ir - id;
            r += ir;
            d += id;
            foo[t * 5 + 0] = s;
            foo[t * 5 + 1] = i;
            foo[t * 5 + 2] = r;
            foo[t * 5 + 3] = d;
            foo[t * 5 + 4] = n;
        }
        out[0] = s;
        out[1] = i;
        out[2] = r;
        out[3] = d;
        out[4] = n;
    }
}

extern "C" void kernel_launch(void* const* d_in, const int* in_sizes, int n_in,
                              void* d_out, int out_size, void* d_ws, size_t ws_size,
                              hipStream_t stream) {
    const float* hu = (const float*)d_in[0];
    const float* sird = (const float*)d_in[1];
    const int* ts = (const int*)d_in[2];
    const float* Wb = (const float*)d_in[3];
    const float* bb = (const float*)d_in[4];
    const float* eWih = (const float*)d_in[5];
    const float* eWhh = (const float*)d_in[6];
    const float* eBih = (const float*)d_in[7];
    const float* eBhh = (const float*)d_in[8];
    const float* dWih = (const float*)d_in[9];
    const float* dWhh = (const float*)d_in[10];
    const float* dBih = (const float*)d_in[11];
    const float* dBhh = (const float*)d_in[12];
    const float* Wa = (const float*)d_in[13];
    const float* ba = (const float*)d_in[14];

    float* wsf = (float*)d_ws;
    int* wsi = (int*)d_ws;
    float* p = wsf + WS_P;
    float* q = wsf + WS_Q;
    float* h_buf = wsf + WS_HBUF;
    float* dx = wsf + WS_DX;
    float* dh = wsf + WS_DH;
    float* beta = wsf + WS_BETA;
    int* flags = wsi + WS_FLAGS;

    hipLaunchKernelGGL(init_ws, dim3(256), dim3(256), 0, stream, wsi + WS_BETA,
                       (WS_FLAGS - WS_BETA) + N_FLAGS);
    hipLaunchKernelGGL(prep_pq, dim3(6144 / 4), dim3(256), 0, stream, eWih, Wb, bb,
                       eBih, p, q);
    hipLaunchKernelGGL(persist, dim3(NWG), dim3(NTH), 0, stream, hu, eWhh, eBhh,
                       dWih, dWhh, dBih, dBhh, Wa, p, q, h_buf, dx, dh, beta, flags);
    hipLaunchKernelGGL(sird_k, dim3(1), dim3(64), 0, stream, sird, ba, ts, beta,
                       (float*)d_out);
}

// Round 2
// 3157.054 us; speedup vs baseline: 5.1451x; 5.1451x over previous
//
#include <hip/hip_runtime.h>
#include <cstdint>
#include <cstddef>

// ---------------------------------------------------------------------------
// EnDeModel: GRU encoder (365 steps) -> GRU decoder (90 steps) -> SIRD rollout
// Persistent-grid design: 256 WGs (one per CU) x 512 threads.
//  - Encoder Whh slice (24 rows) in fp32 registers (3 rows/wave).
//  - Decoder Wih+Whh slice (48 rows) in packed-bf16 registers (6 rows/wave).
//  - gi for the encoder collapses to u_t * p + q (p = Wih@Wb, q = Wih@bb + bih).
//  - Cross-WG sync: monotonic per-WG flag counters in MALL. All data motion
//    uses agent-scope atomics (sc0 sc1 -> bypass L1/L2, serialize at MALL).
//    NO agent fences (they emit whole-L2 writeback/invalidate on gfx950 --
//    that was the 35us/step stall in round 1). Ordering via s_waitcnt vmcnt(0)
//    between data stores and the flag store (same wave, MALL = single
//    serialization point).
//  - Only wave 0 spins (ballot over 256 flags); waves 1-7 park at s_barrier.
// ---------------------------------------------------------------------------

#define HID   2048
#define T_ENC 365
#define F_DEC 90
#define NWG   256
#define NTH   512

// ws layout (4-byte units)
#define WS_P     0                 // p[6144]
#define WS_Q     6144              // q[6144]
#define WS_HBUF  12288             // h_buf[2][2048]
#define WS_DX    16384             // dx[2048]   (decoder x at s=0: raw hp)
#define WS_DH    18432             // dh[2048]   (decoder h at s=0: sigm(hp))
#define WS_DB    20480             // db[2][2048] (decoder hp double-buffer)
#define WS_BETA  24576             // beta_acc[90] (pad to 128)
#define WS_FLAGS 24704             // flags[256] monotonic counters

__device__ __forceinline__ float sigm(float x) {
    return 1.0f / (1.0f + __expf(-x));
}
__device__ __forceinline__ float tanh_f(float x) {
    return 1.0f - 2.0f / (1.0f + __expf(2.0f * x));
}
__device__ __forceinline__ unsigned bf16rne(float f) {
    unsigned x = __float_as_uint(f);
    return (x + 0x7fffu + ((x >> 16) & 1u)) >> 16;
}
__device__ __forceinline__ unsigned packbf(float lo, float hi) {
    return bf16rne(lo) | (bf16rne(hi) << 16);
}

__global__ void init_ws(int* z, int n) {
    for (int i = blockIdx.x * blockDim.x + threadIdx.x; i < n;
         i += gridDim.x * blockDim.x)
        z[i] = 0;
}

// p[r] = enc_Wih[r,:] @ Wb ; q[r] = enc_Wih[r,:] @ bb + enc_bih[r]
__global__ void prep_pq(const float* __restrict__ Wih, const float* __restrict__ Wb,
                        const float* __restrict__ bb, const float* __restrict__ bih,
                        float* __restrict__ p, float* __restrict__ q) {
    int wave = threadIdx.x >> 6, lane = threadIdx.x & 63;
    int row = blockIdx.x * 4 + wave;
    const float* wr = Wih + (size_t)row * HID;
    float ap = 0.f, aq = 0.f;
    for (int k = lane; k < HID; k += 64) {
        float w = wr[k];
        ap += w * Wb[k];
        aq += w * bb[k];
    }
#pragma unroll
    for (int m = 1; m < 64; m <<= 1) {
        ap += __shfl_xor(ap, m);
        aq += __shfl_xor(aq, m);
    }
    if (lane == 0) {
        p[row] = ap;
        q[row] = aq + bih[row];
    }
}

__device__ __forceinline__ int flag_ld(const int* p_) {
    return __hip_atomic_load((int*)p_, __ATOMIC_RELAXED, __HIP_MEMORY_SCOPE_AGENT);
}
__device__ __forceinline__ void flag_st(int* p_, int v) {
    __hip_atomic_store(p_, v, __ATOMIC_RELAXED, __HIP_MEMORY_SCOPE_AGENT);
}
__device__ __forceinline__ float agent_ld(const float* p_) {
    return __hip_atomic_load((float*)p_, __ATOMIC_RELAXED, __HIP_MEMORY_SCOPE_AGENT);
}
__device__ __forceinline__ void agent_st(float* p_, float v) {
    __hip_atomic_store(p_, v, __ATOMIC_RELAXED, __HIP_MEMORY_SCOPE_AGENT);
}

// wave-0-only spin: all 256 monotonic flags >= tgt. Lane l owns flags[4l..4l+3].
__device__ __forceinline__ void poll_flags(const int* flags, int lane, int tgt) {
    const int* my = flags + lane * 4;
    while (true) {
        int a = flag_ld(my + 0);
        int b = flag_ld(my + 1);
        int c = flag_ld(my + 2);
        int d = flag_ld(my + 3);
        bool ok = (a >= tgt) & (b >= tgt) & (c >= tgt) & (d >= tgt);
        if (__ballot(ok) == ~0ull) break;
    }
}

__global__ __launch_bounds__(NTH, 2) void persist(
    const float* __restrict__ hu, const float* __restrict__ encWhh,
    const float* __restrict__ encBhh, const float* __restrict__ decWih,
    const float* __restrict__ decWhh, const float* __restrict__ decBih,
    const float* __restrict__ decBhh, const float* __restrict__ Wa,
    const float* __restrict__ p, const float* __restrict__ q,
    float* h_buf, float* dx, float* dh, float* db, float* beta_acc, int* flags) {
    const int wg = blockIdx.x, tid = threadIdx.x;
    const int wave = tid >> 6, lane = tid & 63;
    const int j0 = wg * 8;

    __shared__ float h_lds[HID], x_lds[HID];
    __shared__ float g_l[48];
    __shared__ float p_l[24], q_l[24], ebhh[24], dbih[24], dbhh[24], wa_l[8];
    __shared__ float u_l[T_ENC];

    // --- LDS preloads (once) ---
    for (int idx = tid; idx < T_ENC; idx += NTH) u_l[idx] = hu[idx];
    if (tid < 24) {
        int g = tid >> 3, jj = tid & 7;
        int r = g * HID + j0 + jj;
        p_l[tid] = p[r];
        q_l[tid] = q[r];
        ebhh[tid] = encBhh[r];
        dbih[tid] = decBih[r];
        dbhh[tid] = decBhh[r];
    }
    if (tid < 8) wa_l[tid] = Wa[j0 + tid];

    // --- encoder Whh slice -> fp32 registers: 3 rows per wave ---
    float4 We[3][8];
#pragma unroll
    for (int rr = 0; rr < 3; rr++) {
        int l = wave * 3 + rr;
        int r = (l >> 3) * HID + j0 + (l & 7);
        const float* base = encWhh + (size_t)r * HID;
#pragma unroll
        for (int i = 0; i < 8; i++)
            We[rr][i] = *reinterpret_cast<const float4*>(base + 4 * lane + 256 * i);
    }
    __syncthreads();

    // =========================== encoder: 365 steps =========================
    for (int t = 0; t < T_ENC; t++) {
        if (t == 0) {
            for (int idx = tid; idx < HID; idx += NTH) h_lds[idx] = 0.f;
            __syncthreads();
        } else {
            if (wave == 0) poll_flags(flags, lane, t);
            __syncthreads();  // release waves 1-7 once wave 0 sees all flags
            const float* src = h_buf + (t & 1) * HID;
#pragma unroll
            for (int ii = 0; ii < 4; ii++) {
                int idx = ii * NTH + tid;
                h_lds[idx] = agent_ld(src + idx);
            }
            __syncthreads();
        }

        float4 hreg[8];
#pragma unroll
        for (int i = 0; i < 8; i++)
            hreg[i] = *reinterpret_cast<const float4*>(&h_lds[4 * lane + 256 * i]);

#pragma unroll
        for (int rr = 0; rr < 3; rr++) {
            float a0 = 0.f, a1 = 0.f, a2 = 0.f, a3 = 0.f;
#pragma unroll
            for (int i = 0; i < 8; i++) {
                float4 w = We[rr][i], h4 = hreg[i];
                a0 += w.x * h4.x;
                a1 += w.y * h4.y;
                a2 += w.z * h4.z;
                a3 += w.w * h4.w;
            }
            float v = (a0 + a1) + (a2 + a3);
#pragma unroll
            for (int m = 1; m < 64; m <<= 1) v += __shfl_xor(v, m);
            if (lane == 0) g_l[wave * 3 + rr] = v;
        }
        __syncthreads();

        if (tid < 8) {
            int jj = tid;
            float u = u_l[t];
            float gir = u * p_l[jj] + q_l[jj];
            float giz = u * p_l[8 + jj] + q_l[8 + jj];
            float gic = u * p_l[16 + jj] + q_l[16 + jj];
            float ghr = g_l[jj] + ebhh[jj];
            float ghz = g_l[8 + jj] + ebhh[8 + jj];
            float ghc = g_l[16 + jj] + ebhh[16 + jj];
            float r = sigm(gir + ghr);
            float z = sigm(giz + ghz);
            float c = tanh_f(gic + r * ghc);
            float hp = (1.f - z) * c + z * h_lds[j0 + jj];
            if (t < T_ENC - 1) {
                agent_st(h_buf + ((t + 1) & 1) * HID + j0 + jj, sigm(hp));
            } else {
                agent_st(dx + j0 + jj, hp);        // y  (raw hp)
                agent_st(dh + j0 + jj, sigm(hp));  // h_enc
            }
        }
        if (wave == 0) {
            // order: h stores (wave 0 lanes 0-7) complete at MALL before flag
            asm volatile("s_waitcnt vmcnt(0)" ::: "memory");
            if (lane == 0) flag_st(flags + wg, t + 1);
        }
    }

    // --- decoder Wih+Whh slice -> packed bf16 registers: 6 rows per wave ---
    unsigned Wd[6][8][2];
#pragma unroll
    for (int rr = 0; rr < 6; rr++) {
        int l = wave * 6 + rr;
        const float* src;
        if (l < 24)
            src = decWih + (size_t)((l >> 3) * HID + j0 + (l & 7)) * HID;
        else {
            int l2 = l - 24;
            src = decWhh + (size_t)((l2 >> 3) * HID + j0 + (l2 & 7)) * HID;
        }
#pragma unroll
        for (int i = 0; i < 8; i++) {
            float4 w = *reinterpret_cast<const float4*>(src + 4 * lane + 256 * i);
            Wd[rr][i][0] = packbf(w.x, w.y);
            Wd[rr][i][1] = packbf(w.z, w.w);
        }
    }

    // =========================== decoder: 90 steps ==========================
    for (int s = 0; s < F_DEC; s++) {
        if (wave == 0) poll_flags(flags, lane, T_ENC + s);
        __syncthreads();
        if (s == 0) {
#pragma unroll
            for (int ii = 0; ii < 4; ii++) {
                int idx = ii * NTH + tid;
                x_lds[idx] = agent_ld(dx + idx);
                h_lds[idx] = agent_ld(dh + idx);
            }
        } else {
            const float* src = db + (s & 1) * HID;
#pragma unroll
            for (int ii = 0; ii < 4; ii++) {
                int idx = ii * NTH + tid;
                h_lds[idx] = agent_ld(src + idx);
            }
        }
        __syncthreads();

        // waves 0-3: Wih rows (x operand); waves 4-7: Whh rows (h operand).
        // For s>=1, x == h == previous hp.
        const float* vsrc = (s == 0 && wave < 4) ? x_lds : h_lds;
        float4 vreg[8];
#pragma unroll
        for (int i = 0; i < 8; i++)
            vreg[i] = *reinterpret_cast<const float4*>(&vsrc[4 * lane + 256 * i]);

#pragma unroll
        for (int rr = 0; rr < 6; rr++) {
            float a0 = 0.f, a1 = 0.f, a2 = 0.f, a3 = 0.f;
#pragma unroll
            for (int i = 0; i < 8; i++) {
                unsigned u0 = Wd[rr][i][0], u1 = Wd[rr][i][1];
                float4 v4 = vreg[i];
                a0 += __uint_as_float(u0 << 16) * v4.x;
                a1 += __uint_as_float(u0 & 0xffff0000u) * v4.y;
                a2 += __uint_as_float(u1 << 16) * v4.z;
                a3 += __uint_as_float(u1 & 0xffff0000u) * v4.w;
            }
            float v = (a0 + a1) + (a2 + a3);
#pragma unroll
            for (int m = 1; m < 64; m <<= 1) v += __shfl_xor(v, m);
            if (lane == 0) g_l[wave * 6 + rr] = v;
        }
        __syncthreads();

        float bc = 0.f;
        if (tid < 8) {
            int jj = tid;
            float gir = g_l[jj] + dbih[jj];
            float giz = g_l[8 + jj] + dbih[8 + jj];
            float gic = g_l[16 + jj] + dbih[16 + jj];
            float ghr = g_l[24 + jj] + dbhh[jj];
            float ghz = g_l[32 + jj] + dbhh[8 + jj];
            float ghc = g_l[40 + jj] + dbhh[16 + jj];
            float r = sigm(gir + ghr);
            float z = sigm(giz + ghz);
            float c = tanh_f(gic + r * ghc);
            float hp = (1.f - z) * c + z * h_lds[j0 + jj];
            agent_st(db + ((s + 1) & 1) * HID + j0 + jj, hp);
            bc = wa_l[jj] * hp;
            bc += __shfl_xor(bc, 1);
            bc += __shfl_xor(bc, 2);
            bc += __shfl_xor(bc, 4);
        }
        if (wave == 0) {
            asm volatile("s_waitcnt vmcnt(0)" ::: "memory");
            if (lane == 0) flag_st(flags + wg, T_ENC + s + 1);
            // beta accumulation off the signal path (after the flag store)
            if (lane == 0) atomicAdd(beta_acc + s, bc);
        }
    }
}

__global__ void sird_k(const float* __restrict__ sird, const float* __restrict__ ba,
                       const int* __restrict__ ts_p,
                       const float* __restrict__ beta_acc, float* __restrict__ out) {
    if (blockIdx.x == 0 && threadIdx.x == 0) {
        float s = sird[0], i = sird[1], r = sird[2], d = sird[3], n = sird[4];
        float bl = 0.f;
        for (int t = 0; t < F_DEC; t++) {
            float b = 1.f / (1.f + expf(-(beta_acc[t] + ba[0])));
            bl = b;
            float si = s * i * b / n, ir = i * 0.05f, id = i * 0.01f;
            s -= si;
            i += si - ir - id;
            r += ir;
            d += id;
        }
        int ts = ts_p[0];
        float* foo = out + 5;
        for (int t = 0; t < ts - 1; t++) {
            float si = s * i * bl / n, ir = i * 0.05f, id = i * 0.01f;
            s -= si;
            i += si - ir - id;
            r += ir;
            d += id;
            foo[t * 5 + 0] = s;
            foo[t * 5 + 1] = i;
            foo[t * 5 + 2] = r;
            foo[t * 5 + 3] = d;
            foo[t * 5 + 4] = n;
        }
        out[0] = s;
        out[1] = i;
        out[2] = r;
        out[3] = d;
        out[4] = n;
    }
}

extern "C" void kernel_launch(void* const* d_in, const int* in_sizes, int n_in,
                              void* d_out, int out_size, void* d_ws, size_t ws_size,
                              hipStream_t stream) {
    const float* hu = (const float*)d_in[0];
    const float* sird = (const float*)d_in[1];
    const int* ts = (const int*)d_in[2];
    const float* Wb = (const float*)d_in[3];
    const float* bb = (const float*)d_in[4];
    const float* eWih = (const float*)d_in[5];
    const float* eWhh = (const float*)d_in[6];
    const float* eBih = (const float*)d_in[7];
    const float* eBhh = (const float*)d_in[8];
    const float* dWih = (const float*)d_in[9];
    const float* dWhh = (const float*)d_in[10];
    const float* dBih = (const float*)d_in[11];
    const float* dBhh = (const float*)d_in[12];
    const float* Wa = (const float*)d_in[13];
    const float* ba = (const float*)d_in[14];

    float* wsf = (float*)d_ws;
    int* wsi = (int*)d_ws;
    float* p = wsf + WS_P;
    float* q = wsf + WS_Q;
    float* h_buf = wsf + WS_HBUF;
    float* dx = wsf + WS_DX;
    float* dh = wsf + WS_DH;
    float* db = wsf + WS_DB;
    float* beta = wsf + WS_BETA;
    int* flags = wsi + WS_FLAGS;

    // zero beta[128 pad] + flags[256]
    hipLaunchKernelGGL(init_ws, dim3(2), dim3(256), 0, stream, wsi + WS_BETA,
                       (WS_FLAGS - WS_BETA) + NWG);
    hipLaunchKernelGGL(prep_pq, dim3(6144 / 4), dim3(256), 0, stream, eWih, Wb, bb,
                       eBih, p, q);
    hipLaunchKernelGGL(persist, dim3(NWG), dim3(NTH), 0, stream, hu, eWhh, eBhh,
                       dWih, dWhh, dBih, dBhh, Wa, p, q, h_buf, dx, dh, db, beta,
                       flags);
    hipLaunchKernelGGL(sird_k, dim3(1), dim3(64), 0, stream, sird, ba, ts, beta,
                       (float*)d_out);
}

// Round 3
// 2499.737 us; speedup vs baseline: 6.4981x; 1.2630x over previous
//
#include <hip/hip_runtime.h>
#include <cstdint>
#include <cstddef>

// ---------------------------------------------------------------------------
// EnDeModel: GRU encoder (365 steps) -> GRU decoder (90 steps) -> SIRD rollout
// Persistent-grid: 256 WGs x 512 threads (8 waves). Wave w of WG g owns hidden
// unit j = g*8+w: all 3 (enc) / 6 (dec) gate rows for j live in that wave's
// registers, so gate math completes in-wave (no cross-wave reduction tail).
//
// Cross-WG handoff: each h element is a 64-bit word {tag=step<<32 | fp32 bits}
// stored/loaded with 8-byte agent-scope atomics (single-copy atomic -> the
// data IS the signal; no flags, no fences, no vmcnt sequencing). Readers poll
// their own elements until tags match. Depth-2 ring is safe: a tag t+2 write
// requires all tag t+1 writes, which require every WG to have read tag t.
//
// Betas: decoder hp rows dumped to hstore[90][2048] (plain stores, off the
// critical path); final kernel does the 90 Wa-dots + 119-step SIRD chain.
// ---------------------------------------------------------------------------

#define HID   2048
#define T_ENC 365
#define F_DEC 90
#define NWG   256
#define NTH   512

// ws layout (4-byte units)
#define WS_P      0                 // p[6144]
#define WS_Q      6144              // q[6144]
#define WS_HBUF   12288             // u64 hbuf[2][2048]  (tagged h ring)
#define WS_DX0    20480             // u64 dx0[2048]      (tagged raw y)
#define WS_HSTORE 24576             // float hstore[90][2048]

typedef unsigned long long u64;

__device__ __forceinline__ float sigm(float x) {
    return 1.0f / (1.0f + __expf(-x));
}
__device__ __forceinline__ float tanh_f(float x) {
    return 1.0f - 2.0f / (1.0f + __expf(2.0f * x));
}
__device__ __forceinline__ unsigned bf16rne(float f) {
    unsigned x = __float_as_uint(f);
    return (x + 0x7fffu + ((x >> 16) & 1u)) >> 16;
}
__device__ __forceinline__ unsigned packbf(float lo, float hi) {
    return bf16rne(lo) | (bf16rne(hi) << 16);
}

__device__ __forceinline__ u64 tld(const u64* p) {
    return __hip_atomic_load((u64*)p, __ATOMIC_RELAXED, __HIP_MEMORY_SCOPE_AGENT);
}
__device__ __forceinline__ void tst(u64* p, u64 v) {
    __hip_atomic_store(p, v, __ATOMIC_RELAXED, __HIP_MEMORY_SCOPE_AGENT);
}
__device__ __forceinline__ u64 mk(unsigned tag, float v) {
    return ((u64)tag << 32) | (u64)__float_as_uint(v);
}

// Each thread polls 4 strided tagged elements; wave exits when all 256 of its
// elements carry `tag`; payloads land in lds[].
__device__ __forceinline__ void poll_to_lds(const u64* __restrict__ buf,
                                            unsigned tag, int tid,
                                            float* __restrict__ lds) {
    u64 x0, x1, x2, x3;
    while (true) {
        x0 = tld(buf + tid);
        x1 = tld(buf + tid + 512);
        x2 = tld(buf + tid + 1024);
        x3 = tld(buf + tid + 1536);
        bool ok = ((unsigned)(x0 >> 32) == tag) & ((unsigned)(x1 >> 32) == tag) &
                  ((unsigned)(x2 >> 32) == tag) & ((unsigned)(x3 >> 32) == tag);
        if (__ballot(ok) == ~0ull) break;
    }
    lds[tid] = __uint_as_float((unsigned)x0);
    lds[tid + 512] = __uint_as_float((unsigned)x1);
    lds[tid + 1024] = __uint_as_float((unsigned)x2);
    lds[tid + 1536] = __uint_as_float((unsigned)x3);
}

// p[r] = enc_Wih[r,:] @ Wb ; q[r] = enc_Wih[r,:] @ bb + enc_bih[r]
__global__ void prep_pq(const float* __restrict__ Wih, const float* __restrict__ Wb,
                        const float* __restrict__ bb, const float* __restrict__ bih,
                        float* __restrict__ p, float* __restrict__ q) {
    int wave = threadIdx.x >> 6, lane = threadIdx.x & 63;
    int row = blockIdx.x * 4 + wave;
    const float* wr = Wih + (size_t)row * HID;
    float ap = 0.f, aq = 0.f;
    for (int k = lane; k < HID; k += 64) {
        float w = wr[k];
        ap += w * Wb[k];
        aq += w * bb[k];
    }
#pragma unroll
    for (int m = 1; m < 64; m <<= 1) {
        ap += __shfl_xor(ap, m);
        aq += __shfl_xor(aq, m);
    }
    if (lane == 0) {
        p[row] = ap;
        q[row] = aq + bih[row];
    }
}

__global__ __launch_bounds__(NTH, 1) void persist(
    const float* __restrict__ hu, const float* __restrict__ encWhh,
    const float* __restrict__ encBhh, const float* __restrict__ decWih,
    const float* __restrict__ decWhh, const float* __restrict__ decBih,
    const float* __restrict__ decBhh, const float* __restrict__ p,
    const float* __restrict__ q, u64* hbuf, u64* dx0, float* hstore) {
    const int wg = blockIdx.x, tid = threadIdx.x;
    const int wave = tid >> 6, lane = tid & 63;
    const int j = wg * 8 + wave;

    __shared__ float h_lds[HID], x_lds[HID];
    __shared__ float p_l[24], q_l[24], ebhh[24], dbih[24], dbhh[24];
    __shared__ float u_l[T_ENC];

    // --- LDS preloads (once) ---
    for (int idx = tid; idx < T_ENC; idx += NTH) u_l[idx] = hu[idx];
    if (tid < 24) {
        int g = tid >> 3, jj = tid & 7;
        int r = g * HID + wg * 8 + jj;
        p_l[tid] = p[r];
        q_l[tid] = q[r];
        ebhh[tid] = encBhh[r];
        dbih[tid] = decBih[r];
        dbhh[tid] = decBhh[r];
    }

    // --- encoder Whh rows for unit j -> fp32 registers (3 rows/wave) ---
    // lane covers k in {4*lane + 256*i + e | i=0..7, e=0..3}
    float4 We[3][8];
#pragma unroll
    for (int g = 0; g < 3; g++) {
        const float* base = encWhh + (size_t)(g * HID + j) * HID;
#pragma unroll
        for (int i = 0; i < 8; i++)
            We[g][i] = *reinterpret_cast<const float4*>(base + 4 * lane + 256 * i);
    }

    // =========================== encoder: 365 steps =========================
    for (int t = 0; t < T_ENC; t++) {
        if (t == 0) {
            for (int idx = tid; idx < HID; idx += NTH) h_lds[idx] = 0.f;
        } else {
            poll_to_lds(hbuf + (t & 1) * HID, (unsigned)t, tid, h_lds);
        }
        __syncthreads();

        float4 hreg[8];
#pragma unroll
        for (int i = 0; i < 8; i++)
            hreg[i] = *reinterpret_cast<const float4*>(&h_lds[4 * lane + 256 * i]);

        float v0, v1, v2;
        {
            float a0 = 0.f, a1 = 0.f, a2 = 0.f, a3 = 0.f;
            float b0 = 0.f, b1 = 0.f, b2 = 0.f, b3 = 0.f;
            float c0 = 0.f, c1 = 0.f, c2 = 0.f, c3 = 0.f;
#pragma unroll
            for (int i = 0; i < 8; i++) {
                float4 h4 = hreg[i];
                float4 wr_ = We[0][i], wz_ = We[1][i], wc_ = We[2][i];
                a0 += wr_.x * h4.x; a1 += wr_.y * h4.y;
                a2 += wr_.z * h4.z; a3 += wr_.w * h4.w;
                b0 += wz_.x * h4.x; b1 += wz_.y * h4.y;
                b2 += wz_.z * h4.z; b3 += wz_.w * h4.w;
                c0 += wc_.x * h4.x; c1 += wc_.y * h4.y;
                c2 += wc_.z * h4.z; c3 += wc_.w * h4.w;
            }
            v0 = (a0 + a1) + (a2 + a3);
            v1 = (b0 + b1) + (b2 + b3);
            v2 = (c0 + c1) + (c2 + c3);
        }
#pragma unroll
        for (int m = 1; m < 64; m <<= 1) {
            v0 += __shfl_xor(v0, m);
            v1 += __shfl_xor(v1, m);
            v2 += __shfl_xor(v2, m);
        }

        if (lane == 0) {
            float u = u_l[t];
            float gir = u * p_l[wave] + q_l[wave];
            float giz = u * p_l[8 + wave] + q_l[8 + wave];
            float gic = u * p_l[16 + wave] + q_l[16 + wave];
            float r = sigm(gir + v0 + ebhh[wave]);
            float z = sigm(giz + v1 + ebhh[8 + wave]);
            float c = tanh_f(gic + r * (v2 + ebhh[16 + wave]));
            float hp = (1.f - z) * c + z * h_lds[j];
            float hs = sigm(hp);
            tst(hbuf + ((t + 1) & 1) * HID + j, mk((unsigned)(t + 1), hs));
            if (t == T_ENC - 1) tst(dx0 + j, mk((unsigned)T_ENC, hp));
        }
    }

    // --- decoder Wih+Whh rows for unit j -> packed bf16 (6 rows/wave) ---
    unsigned Wd[6][8][2];
#pragma unroll
    for (int g = 0; g < 6; g++) {
        const float* src = (g < 3)
            ? decWih + (size_t)(g * HID + j) * HID
            : decWhh + (size_t)((g - 3) * HID + j) * HID;
#pragma unroll
        for (int i = 0; i < 8; i++) {
            float4 w = *reinterpret_cast<const float4*>(src + 4 * lane + 256 * i);
            Wd[g][i][0] = packbf(w.x, w.y);
            Wd[g][i][1] = packbf(w.z, w.w);
        }
    }

    // =========================== decoder: 90 steps ==========================
    for (int s = 0; s < F_DEC; s++) {
        unsigned rt = (unsigned)(T_ENC + s);
        poll_to_lds(hbuf + (rt & 1) * HID, rt, tid, h_lds);
        if (s == 0) poll_to_lds(dx0, (unsigned)T_ENC, tid, x_lds);
        __syncthreads();

        const float* xs = (s == 0) ? x_lds : h_lds;
        float4 vx[8], vh[8];
#pragma unroll
        for (int i = 0; i < 8; i++) {
            vx[i] = *reinterpret_cast<const float4*>(&xs[4 * lane + 256 * i]);
            vh[i] = *reinterpret_cast<const float4*>(&h_lds[4 * lane + 256 * i]);
        }

        float d[6];
#pragma unroll
        for (int g = 0; g < 6; g++) {
            float a0 = 0.f, a1 = 0.f, a2 = 0.f, a3 = 0.f;
#pragma unroll
            for (int i = 0; i < 8; i++) {
                unsigned u0 = Wd[g][i][0], u1 = Wd[g][i][1];
                float4 v4 = (g < 3) ? vx[i] : vh[i];
                a0 += __uint_as_float(u0 << 16) * v4.x;
                a1 += __uint_as_float(u0 & 0xffff0000u) * v4.y;
                a2 += __uint_as_float(u1 << 16) * v4.z;
                a3 += __uint_as_float(u1 & 0xffff0000u) * v4.w;
            }
            d[g] = (a0 + a1) + (a2 + a3);
        }
#pragma unroll
        for (int m = 1; m < 64; m <<= 1) {
#pragma unroll
            for (int g = 0; g < 6; g++) d[g] += __shfl_xor(d[g], m);
        }

        if (lane == 0) {
            float r = sigm(d[0] + dbih[wave] + d[3] + dbhh[wave]);
            float z = sigm(d[1] + dbih[8 + wave] + d[4] + dbhh[8 + wave]);
            float c = tanh_f(d[2] + dbih[16 + wave] +
                             r * (d[5] + dbhh[16 + wave]));
            float hp = (1.f - z) * c + z * h_lds[j];
            tst(hbuf + ((rt + 1) & 1) * HID + j, mk(rt + 1, hp));
            hstore[s * HID + j] = hp;  // off-path, read by sird_k after kernel
        }
    }
}

__global__ void sird_k(const float* __restrict__ sird, const float* __restrict__ Wa,
                       const float* __restrict__ ba, const int* __restrict__ ts_p,
                       const float* __restrict__ hstore, float* __restrict__ out) {
    __shared__ float bpre[96];
    int wave = threadIdx.x >> 6, lane = threadIdx.x & 63;
    const float4* wa4 = (const float4*)Wa;
    for (int s = wave; s < F_DEC; s += 8) {
        const float4* hr = (const float4*)(hstore + (size_t)s * HID);
        float a0 = 0.f, a1 = 0.f, a2 = 0.f, a3 = 0.f;
#pragma unroll
        for (int m = 0; m < 8; m++) {
            float4 w = wa4[lane + 64 * m], h = hr[lane + 64 * m];
            a0 += w.x * h.x;
            a1 += w.y * h.y;
            a2 += w.z * h.z;
            a3 += w.w * h.w;
        }
        float v = (a0 + a1) + (a2 + a3);
#pragma unroll
        for (int m = 1; m < 64; m <<= 1) v += __shfl_xor(v, m);
        if (lane == 0) bpre[s] = v;
    }
    __syncthreads();
    if (threadIdx.x == 0) {
        float s = sird[0], i = sird[1], r = sird[2], d = sird[3], n = sird[4];
        float bl = 0.f;
        for (int t = 0; t < F_DEC; t++) {
            float b = 1.f / (1.f + expf(-(bpre[t] + ba[0])));
            bl = b;
            float si = s * i * b / n, ir = i * 0.05f, id = i * 0.01f;
            s -= si;
            i += si - ir - id;
            r += ir;
            d += id;
        }
        int ts = ts_p[0];
        float* foo = out + 5;
        for (int t = 0; t < ts - 1; t++) {
            float si = s * i * bl / n, ir = i * 0.05f, id = i * 0.01f;
            s -= si;
            i += si - ir - id;
            r += ir;
            d += id;
            foo[t * 5 + 0] = s;
            foo[t * 5 + 1] = i;
            foo[t * 5 + 2] = r;
            foo[t * 5 + 3] = d;
            foo[t * 5 + 4] = n;
        }
        out[0] = s;
        out[1] = i;
        out[2] = r;
        out[3] = d;
        out[4] = n;
    }
}

extern "C" void kernel_launch(void* const* d_in, const int* in_sizes, int n_in,
                              void* d_out, int out_size, void* d_ws, size_t ws_size,
                              hipStream_t stream) {
    const float* hu = (const float*)d_in[0];
    const float* sird = (const float*)d_in[1];
    const int* ts = (const int*)d_in[2];
    const float* Wb = (const float*)d_in[3];
    const float* bb = (const float*)d_in[4];
    const float* eWih = (const float*)d_in[5];
    const float* eWhh = (const float*)d_in[6];
    const float* eBih = (const float*)d_in[7];
    const float* eBhh = (const float*)d_in[8];
    const float* dWih = (const float*)d_in[9];
    const float* dWhh = (const float*)d_in[10];
    const float* dBih = (const float*)d_in[11];
    const float* dBhh = (const float*)d_in[12];
    const float* Wa = (const float*)d_in[13];
    const float* ba = (const float*)d_in[14];

    float* wsf = (float*)d_ws;
    float* p = wsf + WS_P;
    float* q = wsf + WS_Q;
    u64* hbuf = (u64*)(wsf + WS_HBUF);
    u64* dx0 = (u64*)(wsf + WS_DX0);
    float* hstore = wsf + WS_HSTORE;

    // Tags: ws is re-poisoned to 0xAA each launch -> stale tag = 0xAAAAAAAA,
    // never equal to a live tag (1..455), so no flag/buffer init is needed.
    hipLaunchKernelGGL(prep_pq, dim3(6144 / 4), dim3(256), 0, stream, eWih, Wb, bb,
                       eBih, p, q);
    hipLaunchKernelGGL(persist, dim3(NWG), dim3(NTH), 0, stream, hu, eWhh, eBhh,
                       dWih, dWhh, dBih, dBhh, p, q, hbuf, dx0, hstore);
    hipLaunchKernelGGL(sird_k, dim3(1), dim3(NTH), 0, stream, sird, Wa, ba, ts,
                       hstore, (float*)d_out);
}